// Round 10
// baseline (80.587 us; speedup 1.0000x reference)
//
#include <hip/hip_runtime.h>
#include <math.h>

#define DIM 4096
#define H 32
#define D 128
#define SMAX 2048
#define CHUNK 32
#define NCHUNK (SMAX / CHUNK)    // 64
#define PART_STRIDE 132          // acc[128], m, l, pad[2]

typedef float v4f __attribute__((ext_vector_type(4)));

__device__ __forceinline__ float wave_sum(float v) {
#pragma unroll
    for (int o = 32; o; o >>= 1) v += __shfl_xor(v, o);
    return v;
}

// ---------------- fused QKV matvec + RoPE: block per row-pair ----------------
// 6144 blocks x 256 thr. Block b: mat = b>>11 (0=q,1=k,2=v), pr = b&2047,
// rows 2pr, 2pr+1. Proven R1 access pattern (3.17 TB/s logical): 8 w-float4
// + 4 x-float4 per thread, two wave sums, LDS cross-wave reduce, RoPE at end.
__global__ void __launch_bounds__(256) qkv_rope(
        const float* __restrict__ wq, const float* __restrict__ wk,
        const float* __restrict__ wv, const float* __restrict__ x,
        const int* __restrict__ pos_p,
        float* __restrict__ xq, float* __restrict__ xk, float* __restrict__ xv) {
    __shared__ float red[2][4];
    int t = threadIdx.x, lane = t & 63, w = t >> 6;
    int b = blockIdx.x;
    int mat = b >> 11;                 // 0=q 1=k 2=v
    int pr  = b & 2047;
    const float* wm = (mat == 0) ? wq : ((mat == 1) ? wk : wv);
    const float* base = wm + (size_t)pr * 2 * DIM;

    float a0 = 0.f, a1 = 0.f, a2 = 0.f, a3 = 0.f;
    float b0 = 0.f, b1 = 0.f, b2 = 0.f, b3 = 0.f;
#pragma unroll
    for (int i = 0; i < 4; ++i) {
        int idx = i * 1024 + t * 4;
        v4f wa = *reinterpret_cast<const v4f*>(base + idx);
        v4f wb = *reinterpret_cast<const v4f*>(base + DIM + idx);
        v4f xr = *reinterpret_cast<const v4f*>(x + idx);
        a0 = fmaf(wa.x, xr.x, a0);
        a1 = fmaf(wa.y, xr.y, a1);
        a2 = fmaf(wa.z, xr.z, a2);
        a3 = fmaf(wa.w, xr.w, a3);
        b0 = fmaf(wb.x, xr.x, b0);
        b1 = fmaf(wb.y, xr.y, b1);
        b2 = fmaf(wb.z, xr.z, b2);
        b3 = fmaf(wb.w, xr.w, b3);
    }
    float da = wave_sum((a0 + a1) + (a2 + a3));
    float db = wave_sum((b0 + b1) + (b2 + b3));
    if (lane == 0) { red[0][w] = da; red[1][w] = db; }
    __syncthreads();
    if (t == 0) {
        float d0 = red[0][0] + red[0][1] + red[0][2] + red[0][3];
        float d1 = red[1][0] + red[1][1] + red[1][2] + red[1][3];
        if (mat == 2) {
            xv[2 * pr] = d0; xv[2 * pr + 1] = d1;
        } else {
            int pos = *pos_p;
            int j = pr & 63;               // pair index within head
            float theta = powf(10000.0f, -(float)(2 * j) / (float)D);
            float ang = (float)pos * theta;
            float s, c;
            sincosf(ang, &s, &c);
            float* o = (mat == 0) ? xq : xk;
            o[2 * pr]     = d0 * c - d1 * s;
            o[2 * pr + 1] = d0 * s + d1 * c;
        }
    }
}

// ---------------- flash-decode partials (proven) ----------------
__global__ void attn_partial(const float* __restrict__ cache_k, const float* __restrict__ cache_v,
                             const float* __restrict__ xq, const float* __restrict__ xk,
                             const float* __restrict__ xv, const int* __restrict__ pos_p,
                             float* __restrict__ partials) {
    __shared__ float lds_m[4], lds_l[4];
    __shared__ float lds_acc[4][128];
    int h = blockIdx.x;
    int c = blockIdx.y;
    int lane = threadIdx.x;
    int g  = lane >> 4;
    int gl = lane & 15;
    int pos = *pos_p;
    int base = c * CHUNK;
    int p1 = min(base + CHUNK, pos + 1);
    float* pp = partials + (size_t)(h * NCHUNK + c) * PART_STRIDE;

    if (base > pos) {
        if (lane == 0) { pp[128] = -INFINITY; pp[129] = 0.f; }
        reinterpret_cast<float2*>(pp)[lane] = make_float2(0.f, 0.f);
        return;
    }

    const float4* qv = reinterpret_cast<const float4*>(xq + h * D + gl * 8);
    const float4 q0 = qv[0], q1 = qv[1];

    float m = -INFINITY, l = 0.f;
    float4 acc0 = make_float4(0.f, 0.f, 0.f, 0.f);
    float4 acc1 = make_float4(0.f, 0.f, 0.f, 0.f);

    for (int p = base + g; p < p1; p += 4) {
        const float* kp = (p == pos) ? (xk + h * D)
                                     : (cache_k + ((size_t)p * H + h) * D);
        const float4* kv4 = reinterpret_cast<const float4*>(kp + gl * 8);
        float4 k0 = kv4[0], k1 = kv4[1];
        float d = q0.x * k0.x + q0.y * k0.y + q0.z * k0.z + q0.w * k0.w
                + q1.x * k1.x + q1.y * k1.y + q1.z * k1.z + q1.w * k1.w;
        d += __shfl_xor(d, 1);
        d += __shfl_xor(d, 2);
        d += __shfl_xor(d, 4);
        d += __shfl_xor(d, 8);
        float s = d * 0.08838834764831845f;   // 1/sqrt(128)
        float mn = fmaxf(m, s);
        float corr = __expf(m - mn);
        float wgt  = __expf(s - mn);
        const float* vp = (p == pos) ? (xv + h * D)
                                     : (cache_v + ((size_t)p * H + h) * D);
        const float4* vv4 = reinterpret_cast<const float4*>(vp + gl * 8);
        float4 v0 = vv4[0], v1 = vv4[1];
        l = l * corr + wgt;
        acc0.x = fmaf(wgt, v0.x, acc0.x * corr);
        acc0.y = fmaf(wgt, v0.y, acc0.y * corr);
        acc0.z = fmaf(wgt, v0.z, acc0.z * corr);
        acc0.w = fmaf(wgt, v0.w, acc0.w * corr);
        acc1.x = fmaf(wgt, v1.x, acc1.x * corr);
        acc1.y = fmaf(wgt, v1.y, acc1.y * corr);
        acc1.z = fmaf(wgt, v1.z, acc1.z * corr);
        acc1.w = fmaf(wgt, v1.w, acc1.w * corr);
        m = mn;
    }

    if (gl == 0) { lds_m[g] = m; lds_l[g] = l; }
    *reinterpret_cast<float4*>(&lds_acc[g][gl * 8])     = acc0;
    *reinterpret_cast<float4*>(&lds_acc[g][gl * 8 + 4]) = acc1;
    __syncthreads();
    float M = fmaxf(fmaxf(lds_m[0], lds_m[1]), fmaxf(lds_m[2], lds_m[3]));
    float w0 = __expf(lds_m[0] - M);
    float w1 = __expf(lds_m[1] - M);
    float w2 = __expf(lds_m[2] - M);
    float w3 = __expf(lds_m[3] - M);
    float L  = w0 * lds_l[0] + w1 * lds_l[1] + w2 * lds_l[2] + w3 * lds_l[3];
    int d0 = 2 * lane;
    float s0 = w0 * lds_acc[0][d0]     + w1 * lds_acc[1][d0]
             + w2 * lds_acc[2][d0]     + w3 * lds_acc[3][d0];
    float s1 = w0 * lds_acc[0][d0 + 1] + w1 * lds_acc[1][d0 + 1]
             + w2 * lds_acc[2][d0 + 1] + w3 * lds_acc[3][d0 + 1];
    if (lane == 0) { pp[128] = M; pp[129] = L; }
    reinterpret_cast<float2*>(pp)[lane] = make_float2(s0, s1);
}

// ---------------- combine partials per head (proven) ----------------
__global__ void attn_combine(const float* __restrict__ partials, float* __restrict__ out_attn) {
    int h = blockIdx.x;
    int lane = threadIdx.x;
    float m = -INFINITY;
    for (int c = 0; c < NCHUNK; ++c)
        m = fmaxf(m, partials[(size_t)(h * NCHUNK + c) * PART_STRIDE + 128]);
    float L = 0.f, a0 = 0.f, a1 = 0.f;
    for (int c = 0; c < NCHUNK; ++c) {
        const float* pp = partials + (size_t)(h * NCHUNK + c) * PART_STRIDE;
        float mw = pp[128];
        float w = (mw == -INFINITY) ? 0.f : __expf(mw - m);
        L += pp[129] * w;
        float2 a = *reinterpret_cast<const float2*>(pp + 2 * lane);
        a0 += w * a.x;
        a1 += w * a.y;
    }
    float inv = 1.f / L;
    out_attn[h * D + 2 * lane]     = a0 * inv;
    out_attn[h * D + 2 * lane + 1] = a1 * inv;
}

// ---------------- out = Wo @ v : wave per row-pair, pipelined (L3-hot, proven ~7us) ----------------
__device__ __forceinline__ void load_half(v4f (&buf)[8], const float* __restrict__ wp, int off) {
#pragma unroll
    for (int i = 0; i < 8; ++i)
        buf[i] = *reinterpret_cast<const v4f*>(wp + i * 256 + off);
}

template <int XO>
__device__ __forceinline__ float dot_half(const v4f (&buf)[8], const v4f (&xr)[16]) {
    float s0 = 0.f, s1 = 0.f, s2 = 0.f, s3 = 0.f;
#pragma unroll
    for (int i = 0; i < 8; ++i) {
        s0 = fmaf(buf[i].x, xr[XO + i].x, s0);
        s1 = fmaf(buf[i].y, xr[XO + i].y, s1);
        s2 = fmaf(buf[i].z, xr[XO + i].z, s2);
        s3 = fmaf(buf[i].w, xr[XO + i].w, s3);
    }
    return (s0 + s1) + (s2 + s3);
}

#define SB() __builtin_amdgcn_sched_barrier(0)

__global__ void __launch_bounds__(256) matvec_o(
        const float* __restrict__ w_, const float* __restrict__ vin,
        float* __restrict__ y) {
    int t = threadIdx.x, lane = t & 63;
    int W = blockIdx.x * 4 + (t >> 6);
    int r0 = W * 2;
    int off = lane * 4;

    v4f xr[16];
#pragma unroll
    for (int i = 0; i < 16; ++i)
        xr[i] = *reinterpret_cast<const v4f*>(vin + i * 256 + off);

    const float* w0 = w_ + (size_t)r0 * DIM;
    v4f A[8], B[8];
    float d0, d1;
    load_half(A, w0, off);
    load_half(B, w0 + 2048, off);            SB();
    d0  = dot_half<0>(A, xr);
    load_half(A, w0 + DIM, off);             SB();
    d0 += dot_half<8>(B, xr);
    load_half(B, w0 + DIM + 2048, off);      SB();
    d1  = dot_half<0>(A, xr);
    d1 += dot_half<8>(B, xr);

    d0 = wave_sum(d0); d1 = wave_sum(d1);
    if (lane == 0) { y[r0] = d0; y[r0 + 1] = d1; }
}

extern "C" void kernel_launch(void* const* d_in, const int* in_sizes, int n_in,
                              void* d_out, int out_size, void* d_ws, size_t ws_size,
                              hipStream_t stream) {
    const float* x       = (const float*)d_in[0];
    const float* wq      = (const float*)d_in[1];
    const float* wk      = (const float*)d_in[2];
    const float* wv      = (const float*)d_in[3];
    const float* wo      = (const float*)d_in[4];
    const float* cache_k = (const float*)d_in[5];
    const float* cache_v = (const float*)d_in[6];
    const int*   pos     = (const int*)d_in[7];

    float* wsf      = (float*)d_ws;
    float* xq       = wsf;
    float* xk       = wsf + DIM;
    float* xv       = wsf + 2 * DIM;
    float* partials = wsf + 3 * DIM;
    float* out_attn = partials + H * NCHUNK * PART_STRIDE;
    float* y        = (float*)d_out;

    qkv_rope<<<3 * 2048, 256, 0, stream>>>(wq, wk, wv, x, pos, xq, xk, xv);
    attn_partial<<<dim3(H, NCHUNK), 64, 0, stream>>>(cache_k, cache_v, xq, xk, xv, pos, partials);
    attn_combine<<<H, 64, 0, stream>>>(partials, out_attn);
    matvec_o<<<512, 256, 0, stream>>>(wo, out_attn, y);
}

// Round 11
// 77.182 us; speedup vs baseline: 1.0441x; 1.0441x over previous
//
#include <hip/hip_runtime.h>
#include <math.h>

#define DIM 4096
#define H 32
#define D 128
#define SMAX 2048
#define CHUNK 32
#define NCHUNK (SMAX / CHUNK)    // 64
#define PART_STRIDE 132          // acc[128], m, l, pad[2]

typedef float v4f __attribute__((ext_vector_type(4)));

__device__ __forceinline__ float wave_sum(float v) {
#pragma unroll
    for (int o = 32; o; o >>= 1) v += __shfl_xor(v, o);
    return v;
}

// ---------------- QKV matvec + RoPE: wave-per-row-pair, NO barriers in hot path ----------------
// 1536 blocks x 256. Block stages x->LDS once (one barrier), then each of its 4
// waves independently computes one row-pair task: 32 w-float4 loads in a single
// unrolled dependence-free stream (copy-kernel-like), in-wave shuffle reduce only,
// RoPE applied by lane 0. Tests whether cross-wave reduce/barrier was capping the
// outstanding-miss queue.
__global__ void __launch_bounds__(256) qkv_stream(
        const float* __restrict__ wq, const float* __restrict__ wk,
        const float* __restrict__ wv, const float* __restrict__ x,
        const int* __restrict__ pos_p,
        float* __restrict__ xq, float* __restrict__ xk, float* __restrict__ xv) {
    __shared__ float xs[DIM];          // 16 KB
    int t = threadIdx.x, lane = t & 63, w = t >> 6;

#pragma unroll
    for (int i = 0; i < 4; ++i)
        *reinterpret_cast<v4f*>(&xs[(i * 256 + t) * 4]) =
            *reinterpret_cast<const v4f*>(x + (i * 256 + t) * 4);
    __syncthreads();                   // the only barrier

    int task = blockIdx.x * 4 + w;     // 0..6143
    int mat = task >> 11;              // 0=q 1=k 2=v
    int pr  = task & 2047;
    const float* wm = (mat == 0) ? wq : ((mat == 1) ? wk : wv);
    const float* base = wm + (size_t)pr * 2 * DIM;

    float a0 = 0.f, a1 = 0.f, a2 = 0.f, a3 = 0.f;
    float b0 = 0.f, b1 = 0.f, b2 = 0.f, b3 = 0.f;
#pragma unroll
    for (int k = 0; k < 16; ++k) {
        int idx = (k * 64 + lane) * 4;
        v4f wa = *reinterpret_cast<const v4f*>(base + idx);
        v4f wb = *reinterpret_cast<const v4f*>(base + DIM + idx);
        v4f xr = *reinterpret_cast<const v4f*>(&xs[idx]);
        a0 = fmaf(wa.x, xr.x, a0);
        a1 = fmaf(wa.y, xr.y, a1);
        a2 = fmaf(wa.z, xr.z, a2);
        a3 = fmaf(wa.w, xr.w, a3);
        b0 = fmaf(wb.x, xr.x, b0);
        b1 = fmaf(wb.y, xr.y, b1);
        b2 = fmaf(wb.z, xr.z, b2);
        b3 = fmaf(wb.w, xr.w, b3);
    }
    float da = wave_sum((a0 + a1) + (a2 + a3));
    float db = wave_sum((b0 + b1) + (b2 + b3));

    if (lane == 0) {
        if (mat == 2) {
            xv[2 * pr] = da; xv[2 * pr + 1] = db;
        } else {
            int pos = *pos_p;
            int j = pr & 63;               // pair index within head
            float theta = powf(10000.0f, -(float)(2 * j) / (float)D);
            float ang = (float)pos * theta;
            float s, c;
            sincosf(ang, &s, &c);
            float* o = (mat == 0) ? xq : xk;
            o[2 * pr]     = da * c - db * s;
            o[2 * pr + 1] = da * s + db * c;
        }
    }
}

// ---------------- flash-decode partials (proven) ----------------
__global__ void attn_partial(const float* __restrict__ cache_k, const float* __restrict__ cache_v,
                             const float* __restrict__ xq, const float* __restrict__ xk,
                             const float* __restrict__ xv, const int* __restrict__ pos_p,
                             float* __restrict__ partials) {
    __shared__ float lds_m[4], lds_l[4];
    __shared__ float lds_acc[4][128];
    int h = blockIdx.x;
    int c = blockIdx.y;
    int lane = threadIdx.x;
    int g  = lane >> 4;
    int gl = lane & 15;
    int pos = *pos_p;
    int base = c * CHUNK;
    int p1 = min(base + CHUNK, pos + 1);
    float* pp = partials + (size_t)(h * NCHUNK + c) * PART_STRIDE;

    if (base > pos) {
        if (lane == 0) { pp[128] = -INFINITY; pp[129] = 0.f; }
        reinterpret_cast<float2*>(pp)[lane] = make_float2(0.f, 0.f);
        return;
    }

    const float4* qv = reinterpret_cast<const float4*>(xq + h * D + gl * 8);
    const float4 q0 = qv[0], q1 = qv[1];

    float m = -INFINITY, l = 0.f;
    float4 acc0 = make_float4(0.f, 0.f, 0.f, 0.f);
    float4 acc1 = make_float4(0.f, 0.f, 0.f, 0.f);

    for (int p = base + g; p < p1; p += 4) {
        const float* kp = (p == pos) ? (xk + h * D)
                                     : (cache_k + ((size_t)p * H + h) * D);
        const float4* kv4 = reinterpret_cast<const float4*>(kp + gl * 8);
        float4 k0 = kv4[0], k1 = kv4[1];
        float d = q0.x * k0.x + q0.y * k0.y + q0.z * k0.z + q0.w * k0.w
                + q1.x * k1.x + q1.y * k1.y + q1.z * k1.z + q1.w * k1.w;
        d += __shfl_xor(d, 1);
        d += __shfl_xor(d, 2);
        d += __shfl_xor(d, 4);
        d += __shfl_xor(d, 8);
        float s = d * 0.08838834764831845f;   // 1/sqrt(128)
        float mn = fmaxf(m, s);
        float corr = __expf(m - mn);
        float wgt  = __expf(s - mn);
        const float* vp = (p == pos) ? (xv + h * D)
                                     : (cache_v + ((size_t)p * H + h) * D);
        const float4* vv4 = reinterpret_cast<const float4*>(vp + gl * 8);
        float4 v0 = vv4[0], v1 = vv4[1];
        l = l * corr + wgt;
        acc0.x = fmaf(wgt, v0.x, acc0.x * corr);
        acc0.y = fmaf(wgt, v0.y, acc0.y * corr);
        acc0.z = fmaf(wgt, v0.z, acc0.z * corr);
        acc0.w = fmaf(wgt, v0.w, acc0.w * corr);
        acc1.x = fmaf(wgt, v1.x, acc1.x * corr);
        acc1.y = fmaf(wgt, v1.y, acc1.y * corr);
        acc1.z = fmaf(wgt, v1.z, acc1.z * corr);
        acc1.w = fmaf(wgt, v1.w, acc1.w * corr);
        m = mn;
    }

    if (gl == 0) { lds_m[g] = m; lds_l[g] = l; }
    *reinterpret_cast<float4*>(&lds_acc[g][gl * 8])     = acc0;
    *reinterpret_cast<float4*>(&lds_acc[g][gl * 8 + 4]) = acc1;
    __syncthreads();
    float M = fmaxf(fmaxf(lds_m[0], lds_m[1]), fmaxf(lds_m[2], lds_m[3]));
    float w0 = __expf(lds_m[0] - M);
    float w1 = __expf(lds_m[1] - M);
    float w2 = __expf(lds_m[2] - M);
    float w3 = __expf(lds_m[3] - M);
    float L  = w0 * lds_l[0] + w1 * lds_l[1] + w2 * lds_l[2] + w3 * lds_l[3];
    int d0 = 2 * lane;
    float s0 = w0 * lds_acc[0][d0]     + w1 * lds_acc[1][d0]
             + w2 * lds_acc[2][d0]     + w3 * lds_acc[3][d0];
    float s1 = w0 * lds_acc[0][d0 + 1] + w1 * lds_acc[1][d0 + 1]
             + w2 * lds_acc[2][d0 + 1] + w3 * lds_acc[3][d0 + 1];
    if (lane == 0) { pp[128] = M; pp[129] = L; }
    reinterpret_cast<float2*>(pp)[lane] = make_float2(s0, s1);
}

// ---------------- combine partials per head (proven) ----------------
__global__ void attn_combine(const float* __restrict__ partials, float* __restrict__ out_attn) {
    int h = blockIdx.x;
    int lane = threadIdx.x;
    float m = -INFINITY;
    for (int c = 0; c < NCHUNK; ++c)
        m = fmaxf(m, partials[(size_t)(h * NCHUNK + c) * PART_STRIDE + 128]);
    float L = 0.f, a0 = 0.f, a1 = 0.f;
    for (int c = 0; c < NCHUNK; ++c) {
        const float* pp = partials + (size_t)(h * NCHUNK + c) * PART_STRIDE;
        float mw = pp[128];
        float w = (mw == -INFINITY) ? 0.f : __expf(mw - m);
        L += pp[129] * w;
        float2 a = *reinterpret_cast<const float2*>(pp + 2 * lane);
        a0 += w * a.x;
        a1 += w * a.y;
    }
    float inv = 1.f / L;
    out_attn[h * D + 2 * lane]     = a0 * inv;
    out_attn[h * D + 2 * lane + 1] = a1 * inv;
}

// ---------------- out = Wo @ v : wave per row-pair, pipelined (L3-hot, proven) ----------------
__device__ __forceinline__ void load_half(v4f (&buf)[8], const float* __restrict__ wp, int off) {
#pragma unroll
    for (int i = 0; i < 8; ++i)
        buf[i] = *reinterpret_cast<const v4f*>(wp + i * 256 + off);
}

template <int XO>
__device__ __forceinline__ float dot_half(const v4f (&buf)[8], const v4f (&xr)[16]) {
    float s0 = 0.f, s1 = 0.f, s2 = 0.f, s3 = 0.f;
#pragma unroll
    for (int i = 0; i < 8; ++i) {
        s0 = fmaf(buf[i].x, xr[XO + i].x, s0);
        s1 = fmaf(buf[i].y, xr[XO + i].y, s1);
        s2 = fmaf(buf[i].z, xr[XO + i].z, s2);
        s3 = fmaf(buf[i].w, xr[XO + i].w, s3);
    }
    return (s0 + s1) + (s2 + s3);
}

#define SB() __builtin_amdgcn_sched_barrier(0)

__global__ void __launch_bounds__(256) matvec_o(
        const float* __restrict__ w_, const float* __restrict__ vin,
        float* __restrict__ y) {
    int t = threadIdx.x, lane = t & 63;
    int W = blockIdx.x * 4 + (t >> 6);
    int r0 = W * 2;
    int off = lane * 4;

    v4f xr[16];
#pragma unroll
    for (int i = 0; i < 16; ++i)
        xr[i] = *reinterpret_cast<const v4f*>(vin + i * 256 + off);

    const float* w0 = w_ + (size_t)r0 * DIM;
    v4f A[8], B[8];
    float d0, d1;
    load_half(A, w0, off);
    load_half(B, w0 + 2048, off);            SB();
    d0  = dot_half<0>(A, xr);
    load_half(A, w0 + DIM, off);             SB();
    d0 += dot_half<8>(B, xr);
    load_half(B, w0 + DIM + 2048, off);      SB();
    d1  = dot_half<0>(A, xr);
    d1 += dot_half<8>(B, xr);

    d0 = wave_sum(d0); d1 = wave_sum(d1);
    if (lane == 0) { y[r0] = d0; y[r0 + 1] = d1; }
}

extern "C" void kernel_launch(void* const* d_in, const int* in_sizes, int n_in,
                              void* d_out, int out_size, void* d_ws, size_t ws_size,
                              hipStream_t stream) {
    const float* x       = (const float*)d_in[0];
    const float* wq      = (const float*)d_in[1];
    const float* wk      = (const float*)d_in[2];
    const float* wv      = (const float*)d_in[3];
    const float* wo      = (const float*)d_in[4];
    const float* cache_k = (const float*)d_in[5];
    const float* cache_v = (const float*)d_in[6];
    const int*   pos     = (const int*)d_in[7];

    float* wsf      = (float*)d_ws;
    float* xq       = wsf;
    float* xk       = wsf + DIM;
    float* xv       = wsf + 2 * DIM;
    float* partials = wsf + 3 * DIM;
    float* out_attn = partials + H * NCHUNK * PART_STRIDE;
    float* y        = (float*)d_out;

    qkv_stream<<<1536, 256, 0, stream>>>(wq, wk, wv, x, pos, xq, xk, xv);
    attn_partial<<<dim3(H, NCHUNK), 64, 0, stream>>>(cache_k, cache_v, xq, xk, xv, pos, partials);
    attn_combine<<<H, 64, 0, stream>>>(partials, out_attn);
    matvec_o<<<512, 256, 0, stream>>>(wo, out_attn, y);
}